// Round 3
// baseline (280.448 us; speedup 1.0000x reference)
//
#include <hip/hip_runtime.h>

#define NJ 19
#define ROOT_SCALE 200.0f
#define BLOCK 64          // one wave per workgroup: barriers are intra-wave (cheap)
#define CA 12             // chunk A: joints 0..11
#define SS 12             // LDS row stride in float4 (48 floats -> 2-way banks, free)

struct Xform { float r[9]; float t[3]; };

__device__ __forceinline__ void quat_rt(float w, float x, float y, float z,
                                        float tx, float ty, float tz, Xform& o) {
    float ts = 2.0f / (w*w + x*x + y*y + z*z);
    o.r[0] = 1.0f - ts*(y*y + z*z); o.r[1] = ts*(x*y - z*w);        o.r[2] = ts*(x*z + y*w);
    o.r[3] = ts*(x*y + z*w);        o.r[4] = 1.0f - ts*(x*x + z*z); o.r[5] = ts*(y*z - x*w);
    o.r[6] = ts*(x*z - y*w);        o.r[7] = ts*(y*z + x*w);        o.r[8] = 1.0f - ts*(x*x + y*y);
    o.t[0] = o.r[0]*tx + o.r[1]*ty + o.r[2]*tz;
    o.t[1] = o.r[3]*tx + o.r[4]*ty + o.r[5]*tz;
    o.t[2] = o.r[6]*tx + o.r[7]*ty + o.r[8]*tz;
}

// o = p ∘ l : o.r = p.r*l.r ; o.t = p.r*l.t + p.t
__device__ __forceinline__ void compose(const Xform& p, const Xform& l, Xform& o) {
#pragma unroll
    for (int i = 0; i < 3; ++i) {
        o.r[i*3+0] = p.r[i*3+0]*l.r[0] + p.r[i*3+1]*l.r[3] + p.r[i*3+2]*l.r[6];
        o.r[i*3+1] = p.r[i*3+0]*l.r[1] + p.r[i*3+1]*l.r[4] + p.r[i*3+2]*l.r[7];
        o.r[i*3+2] = p.r[i*3+0]*l.r[2] + p.r[i*3+1]*l.r[5] + p.r[i*3+2]*l.r[8];
        o.t[i]     = p.r[i*3+0]*l.t[0] + p.r[i*3+1]*l.t[1] + p.r[i*3+2]*l.t[2] + p.t[i];
    }
}

// one FK step, j known at compile time (unrolled callers)
__device__ __forceinline__ void fk_step(int j, const float4& q, const float* offs,
                                        Xform& cur, Xform& sv0, Xform& sv2,
                                        float rx, float ry, float rz, float4& o) {
    Xform loc;
    float tx = offs[j*16 + 3], ty = offs[j*16 + 7], tz = offs[j*16 + 11];
    quat_rt(q.x, q.y, q.z, q.w, tx, ty, tz, loc);
    if (j == 0) {
        cur = loc;
    } else {
        Xform nxt;
        if (j == 5 || j == 9)        compose(sv2, loc, nxt);   // parent = joint 2
        else if (j == 13 || j == 16) compose(sv0, loc, nxt);   // parent = joint 0
        else                         compose(cur, loc, nxt);   // parent = j-1
        cur = nxt;
    }
    if (j == 0) sv0 = cur;
    if (j == 2) sv2 = cur;
    o.x = cur.t[0] + rx; o.y = cur.t[1] + ry; o.z = cur.t[2] + rz; o.w = 1.0f;
}

__global__ __launch_bounds__(BLOCK, 4) void fk_kernel(
    const float* __restrict__ root, const float* __restrict__ joint,
    const float* __restrict__ offs, float* __restrict__ out, int batch)
{
    __shared__ float4 s4[BLOCK * SS];                    // 12.3 KB -> 13 blocks/CU
    const int t = threadIdx.x;
    const int rowBase = blockIdx.x * BLOCK;
    const int nvalid = min(BLOCK, batch - rowBase);
    const int nv19 = nvalid * NJ;
    const long long slab = (long long)rowBase * NJ;      // float4 index
    const float4* jq = (const float4*)joint + slab;
    float4*       op = (float4*)out        + slab;

    // ---- one fully-coalesced burst: all 19 float4s of the block slab ----
    float4 q[NJ];
#pragma unroll
    for (int i = 0; i < NJ; ++i) {
        int v = i * BLOCK + t;
        if (v < nv19) q[i] = jq[v];
    }
    float rx = 0.f, ry = 0.f, rz = 0.f;
    if (t < nvalid) {
        long long b = rowBase + t;
        rx = root[b*3 + 0] * ROOT_SCALE;
        ry = root[b*3 + 1] * ROOT_SCALE;
        rz = root[b*3 + 2] * ROOT_SCALE;
    }

    // ---- phase A: scatter joints 0..11 into LDS rows ----
#pragma unroll
    for (int i = 0; i < NJ; ++i) {
        int v = i * BLOCK + t, r = v / NJ, c = v % NJ;
        if (v < nv19 && c < CA) s4[r * SS + c] = q[i];
    }
    __syncthreads();

    // ---- compute joints 0..11, overwrite own row in place ----
    Xform cur, sv0, sv2;
    if (t < nvalid) {
        float4* row = &s4[t * SS];
#pragma unroll
        for (int j = 0; j < CA; ++j) {
            float4 o;
            fk_step(j, row[j], offs, cur, sv0, sv2, rx, ry, rz, o);
            row[j] = o;
        }
    }
    __syncthreads();

    // ---- writeback joints 0..11, coalesced ----
#pragma unroll
    for (int i = 0; i < NJ; ++i) {
        int v = i * BLOCK + t, r = v / NJ, c = v % NJ;
        if (v < nv19 && c < CA) op[v] = s4[r * SS + c];
    }
    __syncthreads();

    // ---- phase B: scatter joints 12..18 into the same LDS region ----
#pragma unroll
    for (int i = 0; i < NJ; ++i) {
        int v = i * BLOCK + t, r = v / NJ, c = v % NJ;
        if (v < nv19 && c >= CA) s4[r * SS + (c - CA)] = q[i];
    }
    __syncthreads();

    // ---- compute joints 12..18 (cur carries from j=11; 13,16 use sv0) ----
    if (t < nvalid) {
        float4* row = &s4[t * SS];
#pragma unroll
        for (int j = CA; j < NJ; ++j) {
            float4 o;
            fk_step(j, row[j - CA], offs, cur, sv0, sv2, rx, ry, rz, o);
            row[j - CA] = o;
        }
    }
    __syncthreads();

    // ---- writeback joints 12..18 ----
#pragma unroll
    for (int i = 0; i < NJ; ++i) {
        int v = i * BLOCK + t, r = v / NJ, c = v % NJ;
        if (v < nv19 && c >= CA) op[v] = s4[r * SS + (c - CA)];
    }
}

extern "C" void kernel_launch(void* const* d_in, const int* in_sizes, int n_in,
                              void* d_out, int out_size, void* d_ws, size_t ws_size,
                              hipStream_t stream) {
    const float* root  = (const float*)d_in[0];  // (B,3)
    const float* joint = (const float*)d_in[1];  // (B,76)
    const float* offs  = (const float*)d_in[2];  // (19,4,4)
    float* out = (float*)d_out;                  // (B,19,4)
    const int batch = in_sizes[1] / (NJ * 4);
    const int grid = (batch + BLOCK - 1) / BLOCK;
    fk_kernel<<<grid, BLOCK, 0, stream>>>(root, joint, offs, out, batch);
}

// Round 4
// 158.338 us; speedup vs baseline: 1.7712x; 1.7712x over previous
//
#include <hip/hip_runtime.h>

#define NJ 19
#define ROOT_SCALE 200.0f
#define BLOCK 64          // one wave per workgroup: barriers are intra-wave
#define G 16              // rows per LDS group (16*304B = 38 full 128B lines)
#define NG (BLOCK / G)    // 4 groups
#define SS 21             // LDS row stride in float4 (odd -> 2-way banks, free)
#define GV (G * NJ)       // float4 per group slab = 304

struct Xform { float r[9]; float t[3]; };

__device__ __forceinline__ void quat_rt(float w, float x, float y, float z,
                                        float tx, float ty, float tz, Xform& o) {
    float ts = 2.0f / (w*w + x*x + y*y + z*z);
    o.r[0] = 1.0f - ts*(y*y + z*z); o.r[1] = ts*(x*y - z*w);        o.r[2] = ts*(x*z + y*w);
    o.r[3] = ts*(x*y + z*w);        o.r[4] = 1.0f - ts*(x*x + z*z); o.r[5] = ts*(y*z - x*w);
    o.r[6] = ts*(x*z - y*w);        o.r[7] = ts*(y*z + x*w);        o.r[8] = 1.0f - ts*(x*x + y*y);
    o.t[0] = o.r[0]*tx + o.r[1]*ty + o.r[2]*tz;
    o.t[1] = o.r[3]*tx + o.r[4]*ty + o.r[5]*tz;
    o.t[2] = o.r[6]*tx + o.r[7]*ty + o.r[8]*tz;
}

// o = p ∘ l : o.r = p.r*l.r ; o.t = p.r*l.t + p.t
__device__ __forceinline__ void compose(const Xform& p, const Xform& l, Xform& o) {
#pragma unroll
    for (int i = 0; i < 3; ++i) {
        o.r[i*3+0] = p.r[i*3+0]*l.r[0] + p.r[i*3+1]*l.r[3] + p.r[i*3+2]*l.r[6];
        o.r[i*3+1] = p.r[i*3+0]*l.r[1] + p.r[i*3+1]*l.r[4] + p.r[i*3+2]*l.r[7];
        o.r[i*3+2] = p.r[i*3+0]*l.r[2] + p.r[i*3+1]*l.r[5] + p.r[i*3+2]*l.r[8];
        o.t[i]     = p.r[i*3+0]*l.t[0] + p.r[i*3+1]*l.t[1] + p.r[i*3+2]*l.t[2] + p.t[i];
    }
}

// one FK step; j is a compile-time constant in fully-unrolled callers
__device__ __forceinline__ void fk_step(int j, const float4& q, const float* offs,
                                        Xform& cur, Xform& sv0, Xform& sv2,
                                        float rx, float ry, float rz, float4& o) {
    Xform loc;
    float tx = offs[j*16 + 3], ty = offs[j*16 + 7], tz = offs[j*16 + 11];
    quat_rt(q.x, q.y, q.z, q.w, tx, ty, tz, loc);
    if (j == 0) {
        cur = loc;
    } else {
        Xform nxt;
        if (j == 5 || j == 9)        compose(sv2, loc, nxt);   // parent = joint 2
        else if (j == 13 || j == 16) compose(sv0, loc, nxt);   // parent = joint 0
        else                         compose(cur, loc, nxt);   // parent = j-1
        cur = nxt;
    }
    if (j == 0) sv0 = cur;
    if (j == 2) sv2 = cur;
    o.x = cur.t[0] + rx; o.y = cur.t[1] + ry; o.z = cur.t[2] + rz; o.w = 1.0f;
}

__global__ __launch_bounds__(BLOCK) void fk_kernel(
    const float* __restrict__ root, const float* __restrict__ joint,
    const float* __restrict__ offs, float* __restrict__ out, int batch)
{
    __shared__ float4 s4[G * SS];                       // 5376 B -> LDS never binds
    const int t = threadIdx.x;
    const int rowBase = blockIdx.x * BLOCK;
    const int nvalid = min(BLOCK, batch - rowBase);
    const int nv19 = nvalid * NJ;
    const long long slab = (long long)rowBase * NJ;     // float4 index
    const float4* jq = (const float4*)joint + slab;
    float4*       op = (float4*)out        + slab;

    const int myg = t / G;                              // group carrying my row
    const int myr = t % G;                              // my row within that group

    float rx = 0.f, ry = 0.f, rz = 0.f;
    if (t < nvalid) {
        long long b = rowBase + t;
        rx = root[b*3 + 0] * ROOT_SCALE;
        ry = root[b*3 + 1] * ROOT_SCALE;
        rz = root[b*3 + 2] * ROOT_SCALE;
    }

    float4 q[NJ];

    // ---- input: 4 group phases; global side always coalesced full lines ----
#pragma unroll
    for (int g = 0; g < NG; ++g) {
        const int base = g * GV;
        float4 ld[5];
#pragma unroll
        for (int i = 0; i < 5; ++i) {
            int v = i * BLOCK + t;
            ld[i] = make_float4(0.f, 0.f, 0.f, 0.f);
            if (v < GV && base + v < nv19) ld[i] = jq[base + v];
        }
#pragma unroll
        for (int i = 0; i < 5; ++i) {
            int v = i * BLOCK + t;
            if (v < GV) s4[(v / NJ) * SS + (v % NJ)] = ld[i];
        }
        __syncthreads();
        if (g == myg && t < nvalid) {
#pragma unroll
            for (int j = 0; j < NJ; ++j) q[j] = s4[myr * SS + j];
        }
        __syncthreads();                                // WAR: buffer reused next g
    }

    // ---- compute: whole chain in registers, outputs overwrite inputs ----
    if (t < nvalid) {
        Xform cur, sv0, sv2;
#pragma unroll
        for (int j = 0; j < NJ; ++j) {
            float4 o;
            fk_step(j, q[j], offs, cur, sv0, sv2, rx, ry, rz, o);
            q[j] = o;
        }
    }

    // ---- output: 4 group phases; each group = 38 whole 128B lines, one pass ----
#pragma unroll
    for (int g = 0; g < NG; ++g) {
        if (g == myg && t < nvalid) {
#pragma unroll
            for (int j = 0; j < NJ; ++j) s4[myr * SS + j] = q[j];
        }
        __syncthreads();
        const int base = g * GV;
#pragma unroll
        for (int i = 0; i < 5; ++i) {
            int v = i * BLOCK + t;
            if (v < GV && base + v < nv19) op[base + v] = s4[(v / NJ) * SS + (v % NJ)];
        }
        __syncthreads();                                // WAR: buffer reused next g
    }
}

extern "C" void kernel_launch(void* const* d_in, const int* in_sizes, int n_in,
                              void* d_out, int out_size, void* d_ws, size_t ws_size,
                              hipStream_t stream) {
    const float* root  = (const float*)d_in[0];  // (B,3)
    const float* joint = (const float*)d_in[1];  // (B,76)
    const float* offs  = (const float*)d_in[2];  // (19,4,4)
    float* out = (float*)d_out;                  // (B,19,4)
    const int batch = in_sizes[1] / (NJ * 4);
    const int grid = (batch + BLOCK - 1) / BLOCK;
    fk_kernel<<<grid, BLOCK, 0, stream>>>(root, joint, offs, out, batch);
}